// Round 4
// baseline (125.332 us; speedup 1.0000x reference)
//
#include <hip/hip_runtime.h>
#include <math.h>

#define NB    128
#define CCH   512
#define HW    784       // 28*28
#define NCLS  1000
#define GRP   32        // images per chunk
#define NGRP  4         // 128/32
#define PCHG  16384     // channels per group = 32*512
#define ABLK  12544     // apply blocks per group = 32*512*196/256
#define PBLK  4096      // pool blocks per group = 16384/4

typedef float f32x4 __attribute__((ext_vector_type(4)));

// Fused: blocks [0,aBlk) apply group g-1; blocks [aBlk, aBlk+pBlk) pool group g.
// Chunking keeps feat(g) L3-resident between its pool and its apply.
__global__ __launch_bounds__(256) void k_fused(const float* __restrict__ feat,
                                               float* __restrict__ pooled,
                                               const float* __restrict__ mask,
                                               float* __restrict__ out,
                                               int g, int aBlk) {
    int t = threadIdx.x;
    if ((int)blockIdx.x < aBlk) {
        // ---- apply for group go = g-1 ----
        int go = g - 1;
        unsigned int i = blockIdx.x * 256u + t;            // local f32x4 idx, < 3211264
        unsigned int chl = i / 196u;                       // local channel, < 16384
        float m = mask[go * PCHG + chl];
        size_t gi = (size_t)go * (GRP * CCH * 196) + i;    // global f32x4 idx
        f32x4 v = reinterpret_cast<const f32x4*>(feat)[gi];
        v.x *= m; v.y *= m; v.z *= m; v.w *= m;
        __builtin_nontemporal_store(v, reinterpret_cast<f32x4*>(out) + gi);
    } else {
        // ---- pool for group g ----
        int wv = t >> 6, lane = t & 63;
        int chl = ((int)blockIdx.x - aBlk) * 4 + wv;       // local channel
        int ch = g * PCHG + chl;                           // global (n,c)
        const float* src = feat + (size_t)ch * HW;
        float s = 0.f;
#pragma unroll
        for (int it = 0; it < 3; ++it) {
            f32x4 v = *reinterpret_cast<const f32x4*>(src + it * 256 + lane * 4);
            s += v.x + v.y + v.z + v.w;
        }
        if (lane < 4) {
            f32x4 v = *reinterpret_cast<const f32x4*>(src + 768 + lane * 4);
            s += v.x + v.y + v.z + v.w;
        }
#pragma unroll
        for (int o = 32; o; o >>= 1) s += __shfl_down(s, o, 64);
        if (lane == 0) pooled[ch] = s * (1.0f / 784.0f);
    }
}

// Head for group g (32 images): linear (1000 blocks = 250 cls-grp x 4 n-subgrp of 8)
// + mask (32 blocks).
#define LINB 1000
__global__ __launch_bounds__(256) void k_head(const float* __restrict__ pooled,
                                              const float* __restrict__ w,
                                              const float* __restrict__ b,
                                              const int* __restrict__ y,
                                              float* __restrict__ pred,
                                              float* __restrict__ mask,
                                              int g) {
    __shared__ float sp[4096];
    int t = threadIdx.x, lane = t & 63, wv = t >> 6;

    if (blockIdx.x < LINB) {
        int cb = blockIdx.x % 250;                 // cls group (4 cls)
        int nb = blockIdx.x / 250;                 // n subgroup (8 images)
        int n0 = g * GRP + nb * 8;
        const float* pbase = pooled + (size_t)n0 * CCH;
#pragma unroll
        for (int k = 0; k < 4; ++k)
            *reinterpret_cast<f32x4*>(sp + k * 1024 + t * 4) =
                *reinterpret_cast<const f32x4*>(pbase + k * 1024 + t * 4);
        __syncthreads();

        int cls = cb * 4 + wv;
        const float* wr = w + (size_t)cls * CCH;
        f32x4 a0 = *reinterpret_cast<const f32x4*>(wr + lane * 8);
        f32x4 a1 = *reinterpret_cast<const f32x4*>(wr + lane * 8 + 4);
        float bias = b[cls];
        float s[8];
#pragma unroll
        for (int nn = 0; nn < 8; ++nn) {
            f32x4 p0 = *reinterpret_cast<const f32x4*>(sp + nn * CCH + lane * 8);
            f32x4 p1 = *reinterpret_cast<const f32x4*>(sp + nn * CCH + lane * 8 + 4);
            s[nn] = a0.x * p0.x + a0.y * p0.y + a0.z * p0.z + a0.w * p0.w
                  + a1.x * p1.x + a1.y * p1.y + a1.z * p1.z + a1.w * p1.w;
        }
#pragma unroll
        for (int nn = 0; nn < 8; ++nn) {
            float v = s[nn];
#pragma unroll
            for (int o = 32; o; o >>= 1) v += __shfl_down(v, o, 64);
            if (lane == 0) pred[(size_t)(n0 + nn) * NCLS + cls] = v + bias;
        }
    } else {
        int n = g * GRP + ((int)blockIdx.x - LINB);
        int cls = y[n];
        const float* wr = w + (size_t)cls * CCH;
        const float* pr = pooled + (size_t)n * CCH;
        float g0 = wr[t] * pr[t];
        float g1 = wr[t + 256] * pr[t + 256];

        float ss = g0 * g0 + g1 * g1;
#pragma unroll
        for (int o = 32; o; o >>= 1) ss += __shfl_down(ss, o, 64);
        if (lane == 0) sp[wv] = ss;
        __syncthreads();
        if (t == 0) sp[8] = sqrtf(sp[0] + sp[1] + sp[2] + sp[3]);
        __syncthreads();
        float inv = 11.313708498984761f / sp[8];   // sqrt(512)/2 / norm
        float v0 = 1.0f + g0 * inv, v1 = 1.0f + g1 * inv;
        __syncthreads();

        float mx = fmaxf(v0, v1);
#pragma unroll
        for (int o = 32; o; o >>= 1) mx = fmaxf(mx, __shfl_down(mx, o, 64));
        if (lane == 0) sp[wv] = mx;
        __syncthreads();
        if (t == 0) sp[8] = fmaxf(fmaxf(sp[0], sp[1]), fmaxf(sp[2], sp[3]));
        __syncthreads();
        float m = sp[8];
        float e0 = expf(v0 - m), e1 = expf(v1 - m);
        __syncthreads();

        float se = e0 + e1;
#pragma unroll
        for (int o = 32; o; o >>= 1) se += __shfl_down(se, o, 64);
        if (lane == 0) sp[wv] = se;
        __syncthreads();
        if (t == 0) sp[8] = sp[0] + sp[1] + sp[2] + sp[3];
        __syncthreads();
        float is = 1.0f / sp[8];
        mask[(size_t)n * CCH + t] = e0 * is;
        mask[(size_t)n * CCH + t + 256] = e1 * is;
    }
}

extern "C" void kernel_launch(void* const* d_in, const int* in_sizes, int n_in,
                              void* d_out, int out_size, void* d_ws, size_t ws_size,
                              hipStream_t stream) {
    const float* feat = (const float*)d_in[0];
    const int*   y    = (const int*)d_in[1];
    const float* w    = (const float*)d_in[2];
    const float* b    = (const float*)d_in[3];

    float* out_feat = (float*)d_out;                       // 128*512*784
    float* out_pred = out_feat + (size_t)NB * CCH * HW;    // 128*1000

    float* pooled = (float*)d_ws;                          // 65536 floats
    float* maskp  = pooled + NB * CCH;                     // 65536 floats

    // Pipeline: F0(P0), H0, F1(A0+P1), H1, F2(A1+P2), H2, F3(A2+P3), H3, F4(A3)
    for (int g = 0; g <= NGRP; ++g) {
        int aBlk = (g >= 1) ? ABLK : 0;
        int pBlk = (g < NGRP) ? PBLK : 0;
        k_fused<<<aBlk + pBlk, 256, 0, stream>>>(feat, pooled, maskp, out_feat, g, aBlk);
        if (g < NGRP)
            k_head<<<LINB + GRP, 256, 0, stream>>>(pooled, w, b, y, out_pred, maskp, g);
    }
}

// Round 5
// 105.678 us; speedup vs baseline: 1.1860x; 1.1860x over previous
//
#include <hip/hip_runtime.h>
#include <math.h>

#define NB   128
#define CCH  512
#define HW   784      // 28*28
#define NCLS 1000
#define TOT4 12845056 // 128*512*784/4
#define AB   50176    // apply blocks = TOT4/256

typedef float f32x4 __attribute__((ext_vector_type(4)));

// K1: pooled[n*C+c] = mean over HW. One wave per channel, 4 waves/block.
__global__ __launch_bounds__(256) void k_pool(const float* __restrict__ feat,
                                              float* __restrict__ pooled) {
    int wv = threadIdx.x >> 6, lane = threadIdx.x & 63;
    int ch = blockIdx.x * 4 + wv;              // flat (n,c), < 65536
    const float* src = feat + (size_t)ch * HW;
    float s = 0.f;
#pragma unroll
    for (int it = 0; it < 3; ++it) {           // 3 * 256 floats
        f32x4 v = *reinterpret_cast<const f32x4*>(src + it * 256 + lane * 4);
        s += v.x + v.y + v.z + v.w;
    }
    if (lane < 4) {                            // last 16 floats
        f32x4 v = *reinterpret_cast<const f32x4*>(src + 768 + lane * 4);
        s += v.x + v.y + v.z + v.w;
    }
#pragma unroll
    for (int o = 32; o; o >>= 1) s += __shfl_down(s, o, 64);
    if (lane == 0) pooled[ch] = s * (1.0f / 784.0f);
}

// K2+K3 fused (same as round 3).
#define LIN_BLOCKS 4000
__global__ __launch_bounds__(256) void k_head(const float* __restrict__ pooled,
                                              const float* __restrict__ w,
                                              const float* __restrict__ b,
                                              const int* __restrict__ y,
                                              float* __restrict__ pred,
                                              float* __restrict__ mask) {
    __shared__ float sp[4096];
    int t = threadIdx.x, lane = t & 63, wv = t >> 6;

    if (blockIdx.x < LIN_BLOCKS) {
        int cb = blockIdx.x % 250;             // cls group
        int nb = blockIdx.x / 250;             // n group (8 images)
        const float* pbase = pooled + (size_t)nb * 8 * CCH;
#pragma unroll
        for (int k = 0; k < 4; ++k)            // 4096 floats, 16/thread
            *reinterpret_cast<f32x4*>(sp + k * 1024 + t * 4) =
                *reinterpret_cast<const f32x4*>(pbase + k * 1024 + t * 4);
        __syncthreads();

        int cls = cb * 4 + wv;
        const float* wr = w + (size_t)cls * CCH;
        f32x4 a0 = *reinterpret_cast<const f32x4*>(wr + lane * 8);
        f32x4 a1 = *reinterpret_cast<const f32x4*>(wr + lane * 8 + 4);
        float bias = b[cls];
        float s[8];
#pragma unroll
        for (int nn = 0; nn < 8; ++nn) {
            f32x4 p0 = *reinterpret_cast<const f32x4*>(sp + nn * CCH + lane * 8);
            f32x4 p1 = *reinterpret_cast<const f32x4*>(sp + nn * CCH + lane * 8 + 4);
            s[nn] = a0.x * p0.x + a0.y * p0.y + a0.z * p0.z + a0.w * p0.w
                  + a1.x * p1.x + a1.y * p1.y + a1.z * p1.z + a1.w * p1.w;
        }
#pragma unroll
        for (int nn = 0; nn < 8; ++nn) {
            float v = s[nn];
#pragma unroll
            for (int o = 32; o; o >>= 1) v += __shfl_down(v, o, 64);
            if (lane == 0) pred[(size_t)(nb * 8 + nn) * NCLS + cls] = v + bias;
        }
    } else {
        int n = blockIdx.x - LIN_BLOCKS;
        int cls = y[n];
        const float* wr = w + (size_t)cls * CCH;
        const float* pr = pooled + (size_t)n * CCH;
        float g0 = wr[t] * pr[t];
        float g1 = wr[t + 256] * pr[t + 256];

        float ss = g0 * g0 + g1 * g1;
#pragma unroll
        for (int o = 32; o; o >>= 1) ss += __shfl_down(ss, o, 64);
        if (lane == 0) sp[wv] = ss;
        __syncthreads();
        if (t == 0) sp[8] = sqrtf(sp[0] + sp[1] + sp[2] + sp[3]);
        __syncthreads();
        float inv = 11.313708498984761f / sp[8];   // sqrt(512)/2 / norm
        float v0 = 1.0f + g0 * inv, v1 = 1.0f + g1 * inv;
        __syncthreads();

        float mx = fmaxf(v0, v1);
#pragma unroll
        for (int o = 32; o; o >>= 1) mx = fmaxf(mx, __shfl_down(mx, o, 64));
        if (lane == 0) sp[wv] = mx;
        __syncthreads();
        if (t == 0) sp[8] = fmaxf(fmaxf(sp[0], sp[1]), fmaxf(sp[2], sp[3]));
        __syncthreads();
        float m = sp[8];
        float e0 = expf(v0 - m), e1 = expf(v1 - m);
        __syncthreads();

        float se = e0 + e1;
#pragma unroll
        for (int o = 32; o; o >>= 1) se += __shfl_down(se, o, 64);
        if (lane == 0) sp[wv] = se;
        __syncthreads();
        if (t == 0) sp[8] = sp[0] + sp[1] + sp[2] + sp[3];
        __syncthreads();
        float is = 1.0f / sp[8];
        mask[(size_t)n * CCH + t] = e0 * is;
        mask[(size_t)n * CCH + t + 256] = e1 * is;
    }
}

// K4: out = feat * mask[channel]. REVERSE block order: k_pool streamed feat
// forward, so L3 holds feat with the tail most-recently-used. Reading tail->head
// means the reader consumes newest lines while write-allocations evict oldest
// (head) lines -- avoiding the forward-streaming 0%-hit pathology.
// Lanes within a block stay forward => loads remain fully coalesced.
__global__ __launch_bounds__(256) void k_apply(const float* __restrict__ feat,
                                               const float* __restrict__ mask,
                                               float* __restrict__ out) {
    unsigned int rb = (AB - 1u) - blockIdx.x;           // reversed block index
    unsigned int i = rb * 256u + threadIdx.x;           // f32x4 index, < TOT4
    unsigned int ch = i / 196u;                         // 784/4 f32x4 per channel
    float m = mask[ch];
    f32x4 v = reinterpret_cast<const f32x4*>(feat)[i];
    v.x *= m; v.y *= m; v.z *= m; v.w *= m;
    __builtin_nontemporal_store(v, reinterpret_cast<f32x4*>(out) + i);
}

extern "C" void kernel_launch(void* const* d_in, const int* in_sizes, int n_in,
                              void* d_out, int out_size, void* d_ws, size_t ws_size,
                              hipStream_t stream) {
    const float* feat = (const float*)d_in[0];
    const int*   y    = (const int*)d_in[1];
    const float* w    = (const float*)d_in[2];
    const float* b    = (const float*)d_in[3];

    float* out_feat = (float*)d_out;                       // 128*512*28*28
    float* out_pred = out_feat + (size_t)NB * CCH * HW;    // 128*1000

    float* pooled = (float*)d_ws;                          // 65536 floats
    float* maskp  = pooled + NB * CCH;                     // 65536 floats

    k_pool <<<(NB * CCH) / 4, 256, 0, stream>>>(feat, pooled);
    k_head <<<LIN_BLOCKS + NB, 256, 0, stream>>>(pooled, w, b, y, out_pred, maskp);
    k_apply<<<AB, 256, 0, stream>>>(feat, maskp, out_feat);
}